// Round 13
// baseline (138.819 us; speedup 1.0000x reference)
//
#include <hip/hip_runtime.h>
#include <hip/hip_bf16.h>

// hexagdly conv2d as implicit GEMM with bf16 MFMA.
// R13: 64-co blocks (256 thr, 4 waves), TH=8 x TW=16 tile. LDS = xs 23KB +
// wtb 16.4KB (2x8KB double-buffer) ~= 40KB -> 4 blocks/CU. R5's counted-vmcnt
// weight pipeline and LDS-bounce epilogue kept verbatim (scaled).

#define CIN   64
#define COUT  128
#define COB   64     // co per block
#define HH    256
#define WW    256
#define TH    8
#define TW    16
#define XR    10     // TH + 2 halo rows
#define XC    18     // TW + 2 halo cols

typedef __attribute__((ext_vector_type(8))) short short8;
typedef __attribute__((ext_vector_type(4))) float f32x4;

static __device__ __forceinline__ unsigned short f2bf(float v) {
    __hip_bfloat16 h = __float2bfloat16(v);
    return __builtin_bit_cast(unsigned short, h);
}

typedef __attribute__((address_space(1))) const unsigned int asg_u32;
typedef __attribute__((address_space(3))) unsigned int asl_u32;
static __device__ __forceinline__ void gl2lds16(const void* g, void* l) {
    __builtin_amdgcn_global_load_lds((asg_u32*)g, (asl_u32*)l, 16, 0, 0);
}

#define XS_BYTES   (XR * XC * CIN * 2)               // 23040
#define WTB_OFF    XS_BYTES
#define SMEM_BYTES (XS_BYTES + 2 * COB * CIN * 2)    // 23040 + 16384 = 39424
#define OT_STRIDE  17                                // padded w row (floats)
#define WHALF      (COB * CIN)                       // halfwords per tap-half = 4096

// ---------- pre-kernel: k0/k1 -> bf16 [tap][cohalf][co64][ci], pre-swizzled ----------
__global__ __launch_bounds__(512)
void prep_weights(const float* __restrict__ k0, const float* __restrict__ k1,
                  unsigned short* __restrict__ wsw)
{
    const int idx = blockIdx.x * 512 + threadIdx.x;   // 0..7167
    if (idx >= 7 * COUT * 8) return;
    const int t    = idx >> 10;          // tap 0..6
    const int rem  = idx & 1023;
    const int chf  = rem >> 9;           // co half 0..1
    const int co   = (rem >> 3) & 63;    // local co
    const int ci0  = (idx & 7) * 8;
    const int gco  = chf * 64 + co;
    short8 wv;
    #pragma unroll
    for (int j = 0; j < 8; ++j) {
        const int ci = ci0 + j;
        float v = (t < 3) ? k0[(gco * CIN + ci) * 3 + t]
                          : k1[(gco * CIN + ci) * 4 + (t - 3)];
        wv[j] = (short)f2bf(v);
    }
    const int e = (co * CIN + ci0) ^ ((co & 7) * 8);
    *(short8*)&wsw[(t * 2 + chf) * WHALF + e] = wv;
}

__global__ __launch_bounds__(256, 4)
void hexconv_mfma(const float* __restrict__ x,
                  const unsigned short* __restrict__ wsw,
                  const float* __restrict__ bias,
                  float* __restrict__ out)
{
    __shared__ alignas(16) char smem[SMEM_BYTES];
    __shared__ float bias_lds[COB];
    unsigned short* xs  = (unsigned short*)smem;
    unsigned short* wtb = (unsigned short*)(smem + WTB_OFF);
    float*          ot  = (float*)smem;           // epilogue bounce buffer

    const int tid  = threadIdx.x;
    const int lane = tid & 63;
    const int wid  = tid >> 6;       // 4 waves

    // XCD-aware swizzle: nwg = 8192 = 8 XCD x 1024; each XCD owns one batch image
    const int wg  = (blockIdx.x & 7) * 1024 + (blockIdx.x >> 3);
    const int chf = wg & 1;            // co half 0..1
    const int bx  = (wg >> 1) & 15;    // w tile 0..15
    const int by  = (wg >> 5) & 31;    // h tile 0..31
    const int b   = wg >> 10;          // batch 0..7

    const int co0 = chf * 64;
    const int h0  = by * TH;
    const int w0  = bx * TW;           // even

    // ---- weight staging via async global->LDS (linear dest, pre-swizzled src) ----
    // wave wid owns halfwords [wid*1024, wid*1024+1024) of the 4096-halfword half-tap
    auto stage_tap = [&](int t, int buf) {
        const unsigned short* s0 = wsw + (t * 2 + chf) * WHALF + wid * 1024;
        unsigned short* d0 = wtb + buf * WHALF + wid * 1024;
        gl2lds16(s0 + lane * 8, d0);
        gl2lds16(s0 + 512 + lane * 8, d0 + 512);
    };

    stage_tap(0, 0);   // tap 0 -> buffer 0, overlaps x staging

    if (tid < COB) bias_lds[tid] = bias[co0 + tid];

    // ---------- stage x tile: fp32 -> bf16 (vectorized), ci-contiguous ----------
    {
        const float* xb = x + (size_t)b * CIN * HH * WW;
        // interior cols 1..16 (gw = w0..w0+15): float4 over 4 w, 2 ci per unit
        const int cg = tid & 3;              // col group: gw = w0 + 4*cg + k
        const int u0 = tid >> 2;             // unit: (row, ci-pair), 0..63
        #pragma unroll
        for (int it = 0; it < 5; ++it) {
            const int u   = u0 + it * 64;    // 0..319 = 10 rows x 32 ci-pairs
            const int row = u >> 5;          // 0..9
            const int ci  = (u & 31) * 2;
            const int gh  = h0 - 1 + row;
            f32x4 a = (f32x4)0.0f, c = (f32x4)0.0f;
            if ((unsigned)gh < HH) {
                const float* pb = xb + ((size_t)ci * HH + gh) * WW + w0 + 4 * cg;
                a = *(const f32x4*)pb;
                c = *(const f32x4*)(pb + HH * WW);
            }
            #pragma unroll
            for (int k = 0; k < 4; ++k) {
                const int col = 4 * cg + 1 + k;           // 1..16
                unsigned int pk = (unsigned int)f2bf(a[k]) | ((unsigned int)f2bf(c[k]) << 16);
                const int e = ((row * XC + col) * CIN + ci) ^ ((col & 7) * 8);
                *(unsigned int*)&xs[e] = pk;
            }
        }
        // halo cols: col 0 (gw = w0-1) and col 17 (gw = w0+16)
        for (int i = tid; i < 2 * XR * CIN; i += 256) {   // 1280 elements
            const int side = (i >= XR * CIN) ? 1 : 0;
            const int rem  = i - side * XR * CIN;
            const int row  = rem >> 6;                    // 0..9
            const int ci   = rem & 63;
            const int col  = side ? (XC - 1) : 0;
            const int gh   = h0 - 1 + row;
            const int gw   = side ? (w0 + TW) : (w0 - 1);
            float v = 0.f;
            if ((unsigned)gh < HH && (unsigned)gw < WW)
                v = xb[((size_t)ci * HH + gh) * WW + gw];
            const int e = ((row * XC + col) * CIN + ci) ^ ((col & 7) * 8);
            xs[e] = f2bf(v);
        }
    }

    __syncthreads();   // full drain: tap-0 weights + x tile ready

    // ---------- compute: wave tiling ----------
    const int wn   = wid;            // 4 groups of 2 h-rows
    const int c15  = lane & 15;      // output col (w = w0 + c15)
    const int q8   = (lane >> 4) * 8;
    const int par  = lane & 1;       // parity of output column (w0 even)

    const int aBase = c15 * CIN + q8;
    const int swzA  = (c15 & 7) * 8;

    f32x4 acc[4][2];
    #pragma unroll
    for (int mi = 0; mi < 4; ++mi)
        #pragma unroll
        for (int ni = 0; ni < 2; ++ni)
            acc[mi][ni] = (f32x4)0.0f;

    #pragma unroll
    for (int tap = 0; tap < 7; ++tap) {
        // issue next tap's weight loads; they stay in flight under this tap's MFMAs
        if (tap < 6) {
            stage_tap(tap + 1, (tap + 1) & 1);
            asm volatile("s_waitcnt vmcnt(2)" ::: "memory");   // tap t's loads landed
        } else {
            asm volatile("s_waitcnt vmcnt(0)" ::: "memory");
        }
        __builtin_amdgcn_s_barrier();          // all waves' tap-t weights visible
        __builtin_amdgcn_sched_barrier(0);

        const unsigned short* wc = wtb + (tap & 1) * WHALF;

        // B-operand address parameters for this tap
        int R0, P, C0;
        if (tap < 3) { R0 = tap; P = 0; C0 = 1; }                   // vertical 3x1
        else { R0 = (tap - 3) >> 1; P = 1; C0 = ((tap - 3) & 1) * 2; } // hex 2x2
        const int colb  = c15 + C0;
        const int swzB  = (colb & 7) * 8;
        const int bBase = ((wn * 2 + R0 + P * par) * XC + colb) * CIN + q8;

        #pragma unroll
        for (int ci0 = 0; ci0 < CIN; ci0 += 32) {
            short8 af[4];
            #pragma unroll
            for (int mi = 0; mi < 4; ++mi)
                af[mi] = *(const short8*)&wc[(aBase + mi * 16 * CIN + ci0) ^ swzA];
            #pragma unroll
            for (int ni = 0; ni < 2; ++ni) {
                const int e = (bBase + ni * (XC * CIN) + ci0) ^ swzB;
                short8 bf = *(const short8*)&xs[e];
                #pragma unroll
                for (int mi = 0; mi < 4; ++mi)
                    acc[mi][ni] = __builtin_amdgcn_mfma_f32_16x16x32_bf16(
                        af[mi], bf, acc[mi][ni], 0, 0, 0);
            }
        }

        // all our ds_reads done -> safe for others to overwrite buffers next iter
        asm volatile("s_waitcnt lgkmcnt(0)" ::: "memory");
        __builtin_amdgcn_sched_barrier(0);
        __builtin_amdgcn_s_barrier();
    }

    // ---------- epilogue: LDS bounce for coalesced row stores ----------
    // C/D layout (16x16): col = lane&15, row = (lane>>4)*4 + reg
    // ot = [64 co][8 h][17 pad-w] floats = 34.8KB... (fits: aliases xs+wtb region)
    #pragma unroll
    for (int mi = 0; mi < 4; ++mi) {
        #pragma unroll
        for (int ni = 0; ni < 2; ++ni) {
            const int hh = wn * 2 + ni;
            #pragma unroll
            for (int r = 0; r < 4; ++r) {
                const int col = mi * 16 + (lane >> 4) * 4 + r;   // local co 0..63
                ot[(col * TH + hh) * OT_STRIDE + c15] =
                    acc[mi][ni][r] + bias_lds[col];
            }
        }
    }
    asm volatile("s_waitcnt lgkmcnt(0)" ::: "memory");
    __builtin_amdgcn_sched_barrier(0);
    __builtin_amdgcn_s_barrier();
    // 256 threads x 8 iters = 2048 float4 = 64co x 8h x 16w
    #pragma unroll
    for (int it = 0; it < 8; ++it) {
        const int idx = it * 256 + tid;
        const int w4g = idx & 3;                 // float4 group in row
        const int hh  = (idx >> 2) & 7;
        const int col = idx >> 5;                // local co 0..63
        const float* src = &ot[(col * TH + hh) * OT_STRIDE + w4g * 4];
        f32x4 v = { src[0], src[1], src[2], src[3] };
        __builtin_nontemporal_store(v,
            (f32x4*)&out[(((size_t)b * COUT + co0 + col) * HH + h0 + hh) * WW + w0 + w4g * 4]);
    }
}

extern "C" void kernel_launch(void* const* d_in, const int* in_sizes, int n_in,
                              void* d_out, int out_size, void* d_ws, size_t ws_size,
                              hipStream_t stream) {
    const float* x    = (const float*)d_in[0];
    const float* k0   = (const float*)d_in[1];
    const float* k1   = (const float*)d_in[2];
    const float* bias = (const float*)d_in[3];
    float* out        = (float*)d_out;
    unsigned short* wsw = (unsigned short*)d_ws;   // 7*2*64*64*2 = 114688 B

    prep_weights<<<dim3(14, 1, 1), 512, 0, stream>>>(k0, k1, wsw);
    hexconv_mfma<<<dim3(8192, 1, 1), 256, 0, stream>>>(x, wsw, bias, out);
}